// Round 2
// baseline (305.833 us; speedup 1.0000x reference)
//
#include <hip/hip_runtime.h>

#define N_LHB_C  2000000
#define N_RMHB_C 500000
#define N_LMHB_C 500000
#define STEPS_C  20

typedef float f32x4 __attribute__((ext_vector_type(4)));

__device__ __forceinline__ f32x4 nt_load4(const float* p) {
    return __builtin_nontemporal_load(reinterpret_cast<const f32x4*>(p));
}
__device__ __forceinline__ void nt_store4(float* p, f32x4 v) {
    __builtin_nontemporal_store(v, reinterpret_cast<f32x4*>(p));
}

// One Euler step, exact numpy-f32 evaluation order, contraction-proof.
__device__ __forceinline__ void izh_step(float& v, float& u, float& r, float& acc,
                                         float nz, float i_base) {
    float I = __fadd_rn(i_base, __fmul_rn(nz, 0.5f));
    float t0 = __fmul_rn(__fmul_rn(0.04f, v), v);   // 0.04*v*v
    t0 = __fadd_rn(t0, __fmul_rn(5.0f, v));          // + 5*v
    t0 = __fadd_rn(t0, 140.0f);                      // + 140
    t0 = __fsub_rn(t0, u);                           // - u
    t0 = __fadd_rn(t0, I);                           // + I
    float v2 = __fadd_rn(v, t0);                     // v + (...)
    float inner = __fsub_rn(__fmul_rn(0.2f, v2), u); // B*v2 - u
    float u2 = __fadd_rn(u, __fmul_rn(0.02f, inner));// u + A*(...)
    bool fired = (v2 >= 30.0f);
    v = fired ? -65.0f : v2;
    u = fired ? __fadd_rn(u2, 8.0f) : u2;            // u2 + spk*D
    r = __fadd_rn(__fmul_rn(r, 0.95f), fired ? 0.05f : 0.0f);
    acc += fired ? 1.0f : 0.0f;
}

struct PopPtrs {
    const float* v_in; const float* u_in; const float* rate_in;
    const float* noise; float* spikes_out; float* rate_out; int n;
};

__global__ __launch_bounds__(256) void izh_fused_kernel(
    PopPtrs p0, PopPtrs p1, PopPtrs p2,
    int B0, int B1, int B2,
    const float* __restrict__ frustration,
    const float* __restrict__ reward_p, const float* __restrict__ expref_p,
    const float* __restrict__ aversion_p, const float* __restrict__ da_p,
    const int* __restrict__ goal_p,
    float* __restrict__ partials, unsigned int* __restrict__ counter,
    float* __restrict__ out_tail)
{
    const int tid = threadIdx.x;
    const int bid = blockIdx.x;
    const int NB = B0 + B1 + B2;

    // ---- block -> population mapping (uniform per block) ----
    int mode, lb;
    const float *v_in, *u_in, *rate_in, *noise;
    float *spikes_out, *rate_out;
    int n;
    if (bid < B0)            { mode = 0; lb = bid;
        v_in = p0.v_in; u_in = p0.u_in; rate_in = p0.rate_in; noise = p0.noise;
        spikes_out = p0.spikes_out; rate_out = p0.rate_out; n = p0.n; }
    else if (bid < B0 + B1)  { mode = 1; lb = bid - B0;
        v_in = p1.v_in; u_in = p1.u_in; rate_in = p1.rate_in; noise = p1.noise;
        spikes_out = p1.spikes_out; rate_out = p1.rate_out; n = p1.n; }
    else                     { mode = 2; lb = bid - B0 - B1;
        v_in = p2.v_in; u_in = p2.u_in; rate_in = p2.rate_in; noise = p2.noise;
        spikes_out = p2.spikes_out; rate_out = p2.rate_out; n = p2.n; }

    float i_base;
    {
        const float reward = reward_p[0], expref = expref_p[0], av = aversion_p[0];
        const float rpe = __fsub_rn(reward, expref);
        const float dis = fmaxf(0.0f, -rpe);
        if (mode == 0)      i_base = __fadd_rn(__fmul_rn(dis, 20.0f), -1.0f);
        else if (mode == 1) i_base = __fadd_rn(__fmul_rn(av, 18.0f), -0.5f);
        else                i_base = __fadd_rn(__fmul_rn(av, 10.0f), -1.5f);
    }

    const int base = (lb * 256 + tid) * 4;
    float rsum = 0.0f;

    if (base + 3 < n) {
        f32x4 v4 = nt_load4(v_in + base);
        f32x4 u4 = nt_load4(u_in + base);
        f32x4 r4 = nt_load4(rate_in + base);
        float v[4] = {v4.x, v4.y, v4.z, v4.w};
        float u[4] = {u4.x, u4.y, u4.z, u4.w};
        float r[4] = {r4.x, r4.y, r4.z, r4.w};
        float acc[4] = {0.0f, 0.0f, 0.0f, 0.0f};

        for (int t = 0; t < STEPS_C; ++t) {
            f32x4 nz = nt_load4(noise + (size_t)t * n + base);
            izh_step(v[0], u[0], r[0], acc[0], nz.x, i_base);
            izh_step(v[1], u[1], r[1], acc[1], nz.y, i_base);
            izh_step(v[2], u[2], r[2], acc[2], nz.z, i_base);
            izh_step(v[3], u[3], r[3], acc[3], nz.w, i_base);
        }

        f32x4 ro = {r[0], r[1], r[2], r[3]};
        nt_store4(rate_out + base, ro);
        if (spikes_out) {
            f32x4 so = {acc[0], acc[1], acc[2], acc[3]};
            nt_store4(spikes_out + base, so);
        }
        rsum = __fadd_rn(__fadd_rn(__fadd_rn(r[0], r[1]), r[2]), r[3]);
    } else if (base < n) {
        for (int k = base; k < n && k < base + 4; ++k) {
            float v = v_in[k], u = u_in[k], r = rate_in[k], acc = 0.0f;
            for (int t = 0; t < STEPS_C; ++t)
                izh_step(v, u, r, acc, noise[(size_t)t * n + k], i_base);
            rate_out[k] = r;
            if (spikes_out) spikes_out[k] = acc;
            rsum = __fadd_rn(rsum, r);
        }
    }

    // ---- deterministic block reduction of rate sum ----
    __shared__ float sdata[256];
    __shared__ float s0[256], s1[256], s2[256];
    __shared__ int is_last;
    sdata[tid] = rsum;
    __syncthreads();
    for (int s = 128; s > 0; s >>= 1) {
        if (tid < s) sdata[tid] = __fadd_rn(sdata[tid], sdata[tid + s]);
        __syncthreads();
    }
    if (tid == 0) {
        __hip_atomic_store(&partials[bid], sdata[0],
                           __ATOMIC_RELEASE, __HIP_MEMORY_SCOPE_AGENT);
        unsigned int ticket = __hip_atomic_fetch_add(counter, 1u,
                           __ATOMIC_ACQ_REL, __HIP_MEMORY_SCOPE_AGENT);
        is_last = (ticket == (unsigned int)(NB - 1)) ? 1 : 0;
    }
    __syncthreads();
    if (!is_last) return;

    // ---- last block: final reduction + scalar epilogue ----
    float a = 0.0f, b = 0.0f, c = 0.0f;
    for (int i = tid; i < B0; i += 256)
        a = __fadd_rn(a, __hip_atomic_load(&partials[i],
                      __ATOMIC_RELAXED, __HIP_MEMORY_SCOPE_AGENT));
    for (int i = tid; i < B1; i += 256)
        b = __fadd_rn(b, __hip_atomic_load(&partials[B0 + i],
                      __ATOMIC_RELAXED, __HIP_MEMORY_SCOPE_AGENT));
    for (int i = tid; i < B2; i += 256)
        c = __fadd_rn(c, __hip_atomic_load(&partials[B0 + B1 + i],
                      __ATOMIC_RELAXED, __HIP_MEMORY_SCOPE_AGENT));
    s0[tid] = a; s1[tid] = b; s2[tid] = c;
    __syncthreads();
    for (int s = 128; s > 0; s >>= 1) {
        if (tid < s) {
            s0[tid] = __fadd_rn(s0[tid], s0[tid + s]);
            s1[tid] = __fadd_rn(s1[tid], s1[tid + s]);
            s2[tid] = __fadd_rn(s2[tid], s2[tid + s]);
        }
        __syncthreads();
    }
    if (tid != 0) return;

    const float lhb_mean  = s0[0] / (float)N_LHB_C;
    const float rmhb_mean = s1[0] / (float)N_RMHB_C;
    const float lmhb_mean = s2[0] / (float)N_LMHB_C;
    const float mhb_mean  = __fadd_rn(__fmul_rn(0.67f, rmhb_mean),
                                      __fmul_rn(0.33f, lmhb_mean));

    const float reward = reward_p[0], expref = expref_p[0];
    const float DA = da_p[0];
    const int cg = goal_p[0];

    const float rpe = __fsub_rn(reward, expref);
    const float disappoint = fmaxf(0.0f, -rpe);

    const float da_supp  = fminf(0.5f, __fmul_rn(lhb_mean, 5.0f));
    const float ht5_supp = fminf(0.3f, __fmul_rn(lhb_mean, 3.0f));
    const float ach_ipn  = fminf(1.0f, __fmul_rn(rmhb_mean, 4.0f));
    const float explore  = fminf(1.0f, __fadd_rn(__fmul_rn(disappoint, 2.0f),
                                                 __fmul_rn(lhb_mean, 3.0f)));

    float fr[4];
    for (int i = 0; i < 4; ++i) fr[i] = __fmul_rn(frustration[i], 0.998f);
    fr[cg] = __fadd_rn(fr[cg], (rpe < -0.05f) ? __fmul_rn(0.05f, fabsf(rpe)) : 0.0f);
    fr[cg] = __fmul_rn(fr[cg], (rpe > 0.1f) ? 0.8f : 1.0f);
    for (int i = 0; i < 4; ++i) fr[i] = fminf(fmaxf(fr[i], 0.0f), 1.0f);
    float helplessness = fr[0];
    for (int i = 1; i < 4; ++i) helplessness = fmaxf(helplessness, fr[i]);
    const float sw = (fr[cg] > 0.4f) ? 1.0f : 0.0f;
    fr[cg] = __fmul_rn(fr[cg], (sw > 0.0f) ? 0.3f : 1.0f);

    const float dopa_mod = fmaxf(0.5f, __fmul_rn(2.0f, __fsub_rn(1.0f, DA)));

    out_tail[0]  = disappoint;
    out_tail[1]  = da_supp;
    out_tail[2]  = ht5_supp;
    out_tail[3]  = lhb_mean;
    out_tail[4]  = mhb_mean;
    out_tail[5]  = rmhb_mean;
    out_tail[6]  = lmhb_mean;
    out_tail[7]  = ach_ipn;
    out_tail[8]  = explore;
    out_tail[9]  = sw;
    out_tail[10] = helplessness;
    for (int i = 0; i < 4; ++i)
        out_tail[11 + i] = __fmul_rn(__fmul_rn(fr[i], 0.5f), dopa_mod);
}

extern "C" void kernel_launch(void* const* d_in, const int* in_sizes, int n_in,
                              void* d_out, int out_size, void* d_ws, size_t ws_size,
                              hipStream_t stream) {
    const float* v_lhb    = (const float*)d_in[0];
    const float* u_lhb    = (const float*)d_in[1];
    const float* rate_lhb = (const float*)d_in[2];
    const float* v_rmhb   = (const float*)d_in[3];
    const float* u_rmhb   = (const float*)d_in[4];
    const float* rate_rmhb= (const float*)d_in[5];
    const float* v_lmhb   = (const float*)d_in[6];
    const float* u_lmhb   = (const float*)d_in[7];
    const float* rate_lmhb= (const float*)d_in[8];
    const float* noise_lhb  = (const float*)d_in[9];
    const float* noise_rmhb = (const float*)d_in[10];
    const float* noise_lmhb = (const float*)d_in[11];
    const float* frustration = (const float*)d_in[12];
    const float* reward_p    = (const float*)d_in[13];
    const float* expref_p    = (const float*)d_in[14];
    const float* aversion_p  = (const float*)d_in[15];
    const float* da_p        = (const float*)d_in[16];
    const int*   goal_p      = (const int*)d_in[17];

    const int n_lhb  = in_sizes[0];
    const int n_rmhb = in_sizes[3];
    const int n_lmhb = in_sizes[6];

    float* out = (float*)d_out;
    float* out_lhb_spikes = out;
    float* out_lhb_rate   = out + n_lhb;
    float* out_rmhb_rate  = out + 2 * (size_t)n_lhb;
    float* out_lmhb_rate  = out + 2 * (size_t)n_lhb + n_rmhb;
    float* out_tail       = out + 2 * (size_t)n_lhb + n_rmhb + n_lmhb;

    const int B0 = ((n_lhb  + 3) / 4 + 255) / 256;
    const int B1 = ((n_rmhb + 3) / 4 + 255) / 256;
    const int B2 = ((n_lmhb + 3) / 4 + 255) / 256;
    const int NB = B0 + B1 + B2;

    float* partials = (float*)d_ws;
    unsigned int* counter = (unsigned int*)((char*)d_ws + (size_t)NB * sizeof(float));

    hipMemsetAsync(counter, 0, sizeof(unsigned int), stream);

    PopPtrs p0 = {v_lhb,  u_lhb,  rate_lhb,  noise_lhb,  out_lhb_spikes, out_lhb_rate,  n_lhb};
    PopPtrs p1 = {v_rmhb, u_rmhb, rate_rmhb, noise_rmhb, nullptr,        out_rmhb_rate, n_rmhb};
    PopPtrs p2 = {v_lmhb, u_lmhb, rate_lmhb, noise_lmhb, nullptr,        out_lmhb_rate, n_lmhb};

    izh_fused_kernel<<<NB, 256, 0, stream>>>(
        p0, p1, p2, B0, B1, B2,
        frustration, reward_p, expref_p, aversion_p, da_p, goal_p,
        partials, counter, out_tail);
}

// Round 3
// 57.728 us; speedup vs baseline: 5.2978x; 5.2978x over previous
//
#include <hip/hip_runtime.h>

#define N_LHB_C  2000000
#define N_RMHB_C 500000
#define N_LMHB_C 500000
#define STEPS_C  20

// One Euler step, exact numpy-f32 evaluation order, contraction-proof.
__device__ __forceinline__ void izh_step(float& v, float& u, float& r, float& acc,
                                         float nz, float i_base) {
    float I = __fadd_rn(i_base, __fmul_rn(nz, 0.5f));
    float t0 = __fmul_rn(__fmul_rn(0.04f, v), v);   // 0.04*v*v
    t0 = __fadd_rn(t0, __fmul_rn(5.0f, v));          // + 5*v
    t0 = __fadd_rn(t0, 140.0f);                      // + 140
    t0 = __fsub_rn(t0, u);                           // - u
    t0 = __fadd_rn(t0, I);                           // + I
    float v2 = __fadd_rn(v, t0);                     // v + (...)
    float inner = __fsub_rn(__fmul_rn(0.2f, v2), u); // B*v2 - u
    float u2 = __fadd_rn(u, __fmul_rn(0.02f, inner));// u + A*(...)
    bool fired = (v2 >= 30.0f);
    v = fired ? -65.0f : v2;
    u = fired ? __fadd_rn(u2, 8.0f) : u2;            // u2 + spk*D
    r = __fadd_rn(__fmul_rn(r, 0.95f), fired ? 0.05f : 0.0f);
    acc += fired ? 1.0f : 0.0f;
}

struct PopPtrs {
    const float* v_in; const float* u_in; const float* rate_in;
    const float* noise; float* spikes_out; float* rate_out; int n;
};

__global__ __launch_bounds__(256) void izh_fused_kernel(
    PopPtrs p0, PopPtrs p1, PopPtrs p2,
    int B0, int B1, int B2,
    const float* __restrict__ reward_p, const float* __restrict__ expref_p,
    const float* __restrict__ aversion_p,
    float* __restrict__ partials)
{
    const int tid = threadIdx.x;
    const int bid = blockIdx.x;

    // ---- block -> population mapping (uniform per block) ----
    int mode, lb;
    const float *v_in, *u_in, *rate_in, *noise;
    float *spikes_out, *rate_out;
    int n;
    if (bid < B0)            { mode = 0; lb = bid;
        v_in = p0.v_in; u_in = p0.u_in; rate_in = p0.rate_in; noise = p0.noise;
        spikes_out = p0.spikes_out; rate_out = p0.rate_out; n = p0.n; }
    else if (bid < B0 + B1)  { mode = 1; lb = bid - B0;
        v_in = p1.v_in; u_in = p1.u_in; rate_in = p1.rate_in; noise = p1.noise;
        spikes_out = p1.spikes_out; rate_out = p1.rate_out; n = p1.n; }
    else                     { mode = 2; lb = bid - B0 - B1;
        v_in = p2.v_in; u_in = p2.u_in; rate_in = p2.rate_in; noise = p2.noise;
        spikes_out = p2.spikes_out; rate_out = p2.rate_out; n = p2.n; }

    float i_base;
    {
        const float reward = reward_p[0], expref = expref_p[0], av = aversion_p[0];
        const float rpe = __fsub_rn(reward, expref);
        const float dis = fmaxf(0.0f, -rpe);
        if (mode == 0)      i_base = __fadd_rn(__fmul_rn(dis, 20.0f), -1.0f);
        else if (mode == 1) i_base = __fadd_rn(__fmul_rn(av, 18.0f), -0.5f);
        else                i_base = __fadd_rn(__fmul_rn(av, 10.0f), -1.5f);
    }

    const int base = (lb * 256 + tid) * 4;
    float rsum = 0.0f;

    if (base + 3 < n) {
        float4 v4 = *reinterpret_cast<const float4*>(v_in + base);
        float4 u4 = *reinterpret_cast<const float4*>(u_in + base);
        float4 r4 = *reinterpret_cast<const float4*>(rate_in + base);
        float v[4] = {v4.x, v4.y, v4.z, v4.w};
        float u[4] = {u4.x, u4.y, u4.z, u4.w};
        float r[4] = {r4.x, r4.y, r4.z, r4.w};
        float acc[4] = {0.0f, 0.0f, 0.0f, 0.0f};

        const float* nptr = noise + base;
        #pragma unroll 2
        for (int t = 0; t < STEPS_C; ++t) {
            float4 nz = *reinterpret_cast<const float4*>(nptr);
            nptr += n;
            izh_step(v[0], u[0], r[0], acc[0], nz.x, i_base);
            izh_step(v[1], u[1], r[1], acc[1], nz.y, i_base);
            izh_step(v[2], u[2], r[2], acc[2], nz.z, i_base);
            izh_step(v[3], u[3], r[3], acc[3], nz.w, i_base);
        }

        *reinterpret_cast<float4*>(rate_out + base) = make_float4(r[0], r[1], r[2], r[3]);
        if (spikes_out) {
            *reinterpret_cast<float4*>(spikes_out + base) =
                make_float4(acc[0], acc[1], acc[2], acc[3]);
        }
        rsum = __fadd_rn(__fadd_rn(__fadd_rn(r[0], r[1]), r[2]), r[3]);
    } else if (base < n) {
        for (int k = base; k < n && k < base + 4; ++k) {
            float v = v_in[k], u = u_in[k], r = rate_in[k], acc = 0.0f;
            for (int t = 0; t < STEPS_C; ++t)
                izh_step(v, u, r, acc, noise[(size_t)t * n + k], i_base);
            rate_out[k] = r;
            if (spikes_out) spikes_out[k] = acc;
            rsum = __fadd_rn(rsum, r);
        }
    }

    // ---- deterministic block reduction of rate sum ----
    __shared__ float sdata[256];
    sdata[tid] = rsum;
    __syncthreads();
    for (int s = 128; s > 0; s >>= 1) {
        if (tid < s) sdata[tid] = __fadd_rn(sdata[tid], sdata[tid + s]);
        __syncthreads();
    }
    if (tid == 0) partials[bid] = sdata[0];
}

__global__ __launch_bounds__(256) void finalize_kernel(
    const float* __restrict__ pl, int nl,
    const float* __restrict__ pr, int nr,
    const float* __restrict__ pm, int nm,
    const float* __restrict__ frustration,
    const float* __restrict__ reward_p, const float* __restrict__ expref_p,
    const float* __restrict__ aversion_p, const float* __restrict__ da_p,
    const int* __restrict__ goal_p,
    float* __restrict__ out_tail /* 11 scalars + 4 goal_bias */)
{
    __shared__ float s0[256], s1[256], s2[256];
    const int tid = threadIdx.x;
    float a = 0.0f, b = 0.0f, c = 0.0f;
    for (int i = tid; i < nl; i += 256) a = __fadd_rn(a, pl[i]);
    for (int i = tid; i < nr; i += 256) b = __fadd_rn(b, pr[i]);
    for (int i = tid; i < nm; i += 256) c = __fadd_rn(c, pm[i]);
    s0[tid] = a; s1[tid] = b; s2[tid] = c;
    __syncthreads();
    for (int s = 128; s > 0; s >>= 1) {
        if (tid < s) {
            s0[tid] = __fadd_rn(s0[tid], s0[tid + s]);
            s1[tid] = __fadd_rn(s1[tid], s1[tid + s]);
            s2[tid] = __fadd_rn(s2[tid], s2[tid + s]);
        }
        __syncthreads();
    }
    if (tid != 0) return;

    const float lhb_mean  = s0[0] / (float)N_LHB_C;
    const float rmhb_mean = s1[0] / (float)N_RMHB_C;
    const float lmhb_mean = s2[0] / (float)N_LMHB_C;
    const float mhb_mean  = __fadd_rn(__fmul_rn(0.67f, rmhb_mean),
                                      __fmul_rn(0.33f, lmhb_mean));

    const float reward = reward_p[0], expref = expref_p[0];
    const float DA = da_p[0];
    const int cg = goal_p[0];

    const float rpe = __fsub_rn(reward, expref);
    const float disappoint = fmaxf(0.0f, -rpe);

    const float da_supp  = fminf(0.5f, __fmul_rn(lhb_mean, 5.0f));
    const float ht5_supp = fminf(0.3f, __fmul_rn(lhb_mean, 3.0f));
    const float ach_ipn  = fminf(1.0f, __fmul_rn(rmhb_mean, 4.0f));
    const float explore  = fminf(1.0f, __fadd_rn(__fmul_rn(disappoint, 2.0f),
                                                 __fmul_rn(lhb_mean, 3.0f)));

    float fr[4];
    for (int i = 0; i < 4; ++i) fr[i] = __fmul_rn(frustration[i], 0.998f);
    fr[cg] = __fadd_rn(fr[cg], (rpe < -0.05f) ? __fmul_rn(0.05f, fabsf(rpe)) : 0.0f);
    fr[cg] = __fmul_rn(fr[cg], (rpe > 0.1f) ? 0.8f : 1.0f);
    for (int i = 0; i < 4; ++i) fr[i] = fminf(fmaxf(fr[i], 0.0f), 1.0f);
    float helplessness = fr[0];
    for (int i = 1; i < 4; ++i) helplessness = fmaxf(helplessness, fr[i]);
    const float sw = (fr[cg] > 0.4f) ? 1.0f : 0.0f;
    fr[cg] = __fmul_rn(fr[cg], (sw > 0.0f) ? 0.3f : 1.0f);

    const float dopa_mod = fmaxf(0.5f, __fmul_rn(2.0f, __fsub_rn(1.0f, DA)));

    out_tail[0]  = disappoint;
    out_tail[1]  = da_supp;
    out_tail[2]  = ht5_supp;
    out_tail[3]  = lhb_mean;
    out_tail[4]  = mhb_mean;
    out_tail[5]  = rmhb_mean;
    out_tail[6]  = lmhb_mean;
    out_tail[7]  = ach_ipn;
    out_tail[8]  = explore;
    out_tail[9]  = sw;
    out_tail[10] = helplessness;
    for (int i = 0; i < 4; ++i)
        out_tail[11 + i] = __fmul_rn(__fmul_rn(fr[i], 0.5f), dopa_mod);
}

extern "C" void kernel_launch(void* const* d_in, const int* in_sizes, int n_in,
                              void* d_out, int out_size, void* d_ws, size_t ws_size,
                              hipStream_t stream) {
    const float* v_lhb    = (const float*)d_in[0];
    const float* u_lhb    = (const float*)d_in[1];
    const float* rate_lhb = (const float*)d_in[2];
    const float* v_rmhb   = (const float*)d_in[3];
    const float* u_rmhb   = (const float*)d_in[4];
    const float* rate_rmhb= (const float*)d_in[5];
    const float* v_lmhb   = (const float*)d_in[6];
    const float* u_lmhb   = (const float*)d_in[7];
    const float* rate_lmhb= (const float*)d_in[8];
    const float* noise_lhb  = (const float*)d_in[9];
    const float* noise_rmhb = (const float*)d_in[10];
    const float* noise_lmhb = (const float*)d_in[11];
    const float* frustration = (const float*)d_in[12];
    const float* reward_p    = (const float*)d_in[13];
    const float* expref_p    = (const float*)d_in[14];
    const float* aversion_p  = (const float*)d_in[15];
    const float* da_p        = (const float*)d_in[16];
    const int*   goal_p      = (const int*)d_in[17];

    const int n_lhb  = in_sizes[0];
    const int n_rmhb = in_sizes[3];
    const int n_lmhb = in_sizes[6];

    float* out = (float*)d_out;
    float* out_lhb_spikes = out;
    float* out_lhb_rate   = out + n_lhb;
    float* out_rmhb_rate  = out + 2 * (size_t)n_lhb;
    float* out_lmhb_rate  = out + 2 * (size_t)n_lhb + n_rmhb;
    float* out_tail       = out + 2 * (size_t)n_lhb + n_rmhb + n_lmhb;

    const int B0 = ((n_lhb  + 3) / 4 + 255) / 256;
    const int B1 = ((n_rmhb + 3) / 4 + 255) / 256;
    const int B2 = ((n_lmhb + 3) / 4 + 255) / 256;
    const int NB = B0 + B1 + B2;

    float* partials = (float*)d_ws;

    PopPtrs p0 = {v_lhb,  u_lhb,  rate_lhb,  noise_lhb,  out_lhb_spikes, out_lhb_rate,  n_lhb};
    PopPtrs p1 = {v_rmhb, u_rmhb, rate_rmhb, noise_rmhb, nullptr,        out_rmhb_rate, n_rmhb};
    PopPtrs p2 = {v_lmhb, u_lmhb, rate_lmhb, noise_lmhb, nullptr,        out_lmhb_rate, n_lmhb};

    izh_fused_kernel<<<NB, 256, 0, stream>>>(
        p0, p1, p2, B0, B1, B2,
        reward_p, expref_p, aversion_p, partials);

    finalize_kernel<<<1, 256, 0, stream>>>(
        partials, B0, partials + B0, B1, partials + B0 + B1, B2,
        frustration, reward_p, expref_p, aversion_p, da_p, goal_p,
        out_tail);
}